// Round 8
// baseline (184.456 us; speedup 1.0000x reference)
//
#include <hip/hip_runtime.h>
#include <math.h>

#define Tt 4096
#define Cc 1024
#define Hh 64

typedef __attribute__((ext_vector_type(8))) short bf16x8;
typedef __attribute__((ext_vector_type(4))) float f32x4;
typedef unsigned int u32;

__device__ inline unsigned short f2bf(float f) {
    unsigned u = __float_as_uint(f);
    u = (u + 0x7FFFu + ((u >> 16) & 1u)) >> 16;   // RNE
    return (unsigned short)u;
}

__device__ inline u32 pk2bf(float a, float b) {
#if __has_builtin(__builtin_amdgcn_cvt_pk_bf16_f32)
    typedef __attribute__((ext_vector_type(2))) __bf16 bf16x2_t;
    bf16x2_t v = __builtin_amdgcn_cvt_pk_bf16_f32(a, b);
    return __builtin_bit_cast(u32, v);
#else
    return (u32)f2bf(a) | ((u32)f2bf(b) << 16);
#endif
}

__device__ inline bf16x8 pack8(float4 lo, float4 hi) {
    union { u32 u[4]; bf16x8 v; } r;
    r.u[0] = pk2bf(lo.x, lo.y); r.u[1] = pk2bf(lo.z, lo.w);
    r.u[2] = pk2bf(hi.x, hi.y); r.u[3] = pk2bf(hi.z, hi.w);
    return r.v;
}

// ---------- W^T bf16 [192][1024] (kScale folded into Wq) ----------
__global__ __launch_bounds__(256) void wt_build(
    const float* __restrict__ Wq, const float* __restrict__ Wk,
    const float* __restrict__ Wv, unsigned short* __restrict__ Wt)
{
    int e = blockIdx.x * 256 + threadIdx.x;   // 0..196607
    int k = e & 1023, n = e >> 10;
    float v;
    if (n < 64)       v = Wq[k * 64 + n] * 0.03125f;   // fold 1024^-0.5 into Q
    else if (n < 128) v = Wk[k * 64 + (n - 64)];
    else              v = Wv[k * 64 + (n - 128)];
    Wt[n * 1024 + k] = f2bf(v);
}

// ---------- QKV GEMM: register-resident depth-2 pipeline, no LDS, no barriers ----------
// 512 blocks x 4 waves; tile 32M x 192N; BK=64 (16 steps, fully unrolled).
// Wave w owns n-tiles 3w..3w+2. __launch_bounds__(256,2): 256-VGPR budget so the
// two prefetch slots (A: 8 float4 + B: 6 bf16x8 each, ~56 VGPR/slot) live in
// registers. Round 3/7 lesson: without this the compiler self-caps at 44-56 VGPR
// and sinks the loads -> full mem latency every step -> 3x slower.
__global__ __launch_bounds__(256, 2) void qkv_gemm(
    const float* __restrict__ x, const unsigned short* __restrict__ wt,
    unsigned short* __restrict__ qb, unsigned short* __restrict__ kb,
    unsigned short* __restrict__ vt)
{
    const int t = threadIdx.x, w = t >> 6, lane = t & 63;
    const int col = lane & 15, quad = lane >> 4;
    const int rowbase = (int)blockIdx.x * 32;

    const float* aR0 = x + (long)(rowbase + col) * Cc + quad * 8;        // m-tile 0 row
    const float* aR1 = x + (long)(rowbase + 16 + col) * Cc + quad * 8;   // m-tile 1 row
    const unsigned short* bR0 = wt + (long)((3 * w + 0) * 16 + col) * Cc + quad * 8;
    const unsigned short* bR1 = wt + (long)((3 * w + 1) * 16 + col) * Cc + quad * 8;
    const unsigned short* bR2 = wt + (long)((3 * w + 2) * 16 + col) * Cc + quad * 8;

    float4 ar[2][8];     // [slot][m*4 + kc*2 + half]
    bf16x8 br[2][6];     // [slot][nt*2 + kc]
    f32x4 acc[2][3];
#pragma unroll
    for (int mt = 0; mt < 2; ++mt)
#pragma unroll
        for (int nt = 0; nt < 3; ++nt) acc[mt][nt] = (f32x4){0.f, 0.f, 0.f, 0.f};

    auto issue = [&](int slot, int kk) {
#pragma unroll
        for (int kc = 0; kc < 2; ++kc) {
            int ko = kk + kc * 32;
            ar[slot][0 + kc * 2] = *(const float4*)(aR0 + ko);
            ar[slot][1 + kc * 2] = *(const float4*)(aR0 + ko + 4);
            ar[slot][4 + kc * 2] = *(const float4*)(aR1 + ko);
            ar[slot][5 + kc * 2] = *(const float4*)(aR1 + ko + 4);
            br[slot][0 + kc]     = *(const bf16x8*)(bR0 + ko);
            br[slot][2 + kc]     = *(const bf16x8*)(bR1 + ko);
            br[slot][4 + kc]     = *(const bf16x8*)(bR2 + ko);
        }
    };

    issue(0, 0);
    issue(1, 64);

#pragma unroll
    for (int s = 0; s < 16; ++s) {
        const int sl = s & 1;
        bf16x8 af[2][2];
        af[0][0] = pack8(ar[sl][0], ar[sl][1]);
        af[0][1] = pack8(ar[sl][2], ar[sl][3]);
        af[1][0] = pack8(ar[sl][4], ar[sl][5]);
        af[1][1] = pack8(ar[sl][6], ar[sl][7]);
#pragma unroll
        for (int nt = 0; nt < 3; ++nt)
#pragma unroll
            for (int kc = 0; kc < 2; ++kc) {
                acc[0][nt] = __builtin_amdgcn_mfma_f32_16x16x32_bf16(af[0][kc], br[sl][nt * 2 + kc], acc[0][nt], 0, 0, 0);
                acc[1][nt] = __builtin_amdgcn_mfma_f32_16x16x32_bf16(af[1][kc], br[sl][nt * 2 + kc], acc[1][nt], 0, 0, 0);
            }
        if (s + 2 < 16) issue(sl, (s + 2) * 64);
    }

    // epilogue: C layout col=lane&15, row=quad*4+reg
    const long b = rowbase >> 12;
    const int tloc0 = (rowbase & 4095) + quad * 4;
#pragma unroll
    for (int mt = 0; mt < 2; ++mt)
#pragma unroll
        for (int nt = 0; nt < 3; ++nt) {
            int ng = 3 * w + nt, n = ng * 16 + col;
            int row = rowbase + mt * 16 + quad * 4;
            if (ng < 4) {
#pragma unroll
                for (int reg = 0; reg < 4; ++reg)
                    qb[(long)(row + reg) * Hh + n] = f2bf(acc[mt][nt][reg]);
            } else if (ng < 8) {
#pragma unroll
                for (int reg = 0; reg < 4; ++reg)
                    kb[(long)(row + reg) * Hh + (n - 64)] = f2bf(acc[mt][nt][reg]);
            } else {
                int h = n - 128;
                ushort4 pk = { f2bf(acc[mt][nt][0]), f2bf(acc[mt][nt][1]),
                               f2bf(acc[mt][nt][2]), f2bf(acc[mt][nt][3]) };
                *(ushort4*)&vt[b * Hh * Tt + (long)h * Tt + tloc0 + mt * 16] = pk;
            }
        }
}

// ---------- flash attention (round-4 proven config) ----------
// 1024 blocks = 512 tiles x 2 key-halves, LPT order. Static-max softmax, barrier-free K-loop.
// pl in its OWN LDS region (total 49.7 KB -> compiler targets 3 blocks/CU -> ~168 VGPR budget
// -> no in-loop spills). DO NOT shrink LDS below ~41 KB (rounds 5/6: spill regression).
#define LDP 56
#define LDO 68

__global__ __launch_bounds__(256) void attn(
    const unsigned short* __restrict__ qg, const unsigned short* __restrict__ kg,
    const unsigned short* __restrict__ vtg,
    float* __restrict__ po, float* __restrict__ pls)
{
    __shared__ __align__(16) char smem[49664];
    float* o_red       = (float*)smem;                      // 34816 B
    float* lred        = (float*)(smem + 34816);            // 512 B
    unsigned short* pl = (unsigned short*)(smem + 35328);   // 14336 B

    const int p    = blockIdx.x;
    const int qt   = 127 - (p >> 3);
    const int b    = p & 3;
    const int half = (p >> 2) & 1;
    const int tid  = (b << 7) | qt;
    const long qrow0 = (long)b * Tt + qt * 32;
    const int nkt = qt + 1;
    const int n0  = (nkt + 1) >> 1;
    const int cnt = half ? (nkt - n0) : n0;
    const int ust = half ? n0 : 0;

    const int t = threadIdx.x, w = t >> 6, lane = t & 63;
    const int col = lane & 15, quad = lane >> 4;
    const int plbase = w * 32 * LDP;

    bf16x8 qf[2][2];
#pragma unroll
    for (int mt = 0; mt < 2; ++mt)
#pragma unroll
        for (int kc = 0; kc < 2; ++kc)
            qf[mt][kc] = *(const bf16x8*)&qg[(qrow0 + mt * 16 + col) * Hh + kc * 32 + quad * 8];

    f32x4 oacc[2][4];
#pragma unroll
    for (int mt = 0; mt < 2; ++mt)
#pragma unroll
        for (int nt = 0; nt < 4; ++nt) oacc[mt][nt] = (f32x4){0.f, 0.f, 0.f, 0.f};
    float lsum[2][4] = {{0.f,0.f,0.f,0.f},{0.f,0.f,0.f,0.f}};

    for (int iu = w; iu < cnt; iu += 4) {
        const int u = ust + iu;
        const long krow0 = (long)b * Tt + u * 32;
        bf16x8 kf[2][2];
#pragma unroll
        for (int nt = 0; nt < 2; ++nt)
#pragma unroll
            for (int kc = 0; kc < 2; ++kc)
                kf[nt][kc] = *(const bf16x8*)&kg[(krow0 + nt * 16 + col) * Hh + kc * 32 + quad * 8];
        f32x4 s[2][2];
#pragma unroll
        for (int mt = 0; mt < 2; ++mt)
#pragma unroll
            for (int nt = 0; nt < 2; ++nt) {
                s[mt][nt] = (f32x4){0.f, 0.f, 0.f, 0.f};
#pragma unroll
                for (int kc = 0; kc < 2; ++kc)
                    s[mt][nt] = __builtin_amdgcn_mfma_f32_16x16x32_bf16(qf[mt][kc], kf[nt][kc], s[mt][nt], 0, 0, 0);
            }
#pragma unroll
        for (int mt = 0; mt < 2; ++mt)
#pragma unroll
            for (int reg = 0; reg < 4; ++reg) {
                int rloc = mt * 16 + quad * 4 + reg;
                if (u == qt) {                       // diagonal: mask key_local > row_local
                    if (col > rloc)      s[mt][0][reg] = -INFINITY;
                    if (16 + col > rloc) s[mt][1][reg] = -INFINITY;
                }
                float p0 = __expf(s[mt][0][reg]);
                float p1 = __expf(s[mt][1][reg]);
                lsum[mt][reg] += p0 + p1;
                pl[plbase + rloc * LDP + col]      = f2bf(p0);
                pl[plbase + rloc * LDP + 16 + col] = f2bf(p1);
            }
        bf16x8 af0 = *(const bf16x8*)&pl[plbase + col * LDP + quad * 8];
        bf16x8 af1 = *(const bf16x8*)&pl[plbase + (16 + col) * LDP + quad * 8];
#pragma unroll
        for (int nt = 0; nt < 4; ++nt) {
            bf16x8 vf = *(const bf16x8*)&vtg[((long)b * Hh + nt * 16 + col) * Tt + u * 32 + quad * 8];
            oacc[0][nt] = __builtin_amdgcn_mfma_f32_16x16x32_bf16(af0, vf, oacc[0][nt], 0, 0, 0);
            oacc[1][nt] = __builtin_amdgcn_mfma_f32_16x16x32_bf16(af1, vf, oacc[1][nt], 0, 0, 0);
        }
    }

#pragma unroll
    for (int mt = 0; mt < 2; ++mt)
#pragma unroll
        for (int reg = 0; reg < 4; ++reg) {
            float l = lsum[mt][reg];
            l += __shfl_xor(l, 1); l += __shfl_xor(l, 2);
            l += __shfl_xor(l, 4); l += __shfl_xor(l, 8);
            if (col == 0) lred[w * 32 + mt * 16 + quad * 4 + reg] = l;
        }
#pragma unroll
    for (int mt = 0; mt < 2; ++mt)
#pragma unroll
        for (int nt = 0; nt < 4; ++nt)
#pragma unroll
            for (int reg = 0; reg < 4; ++reg)
                o_red[(w * 32 + mt * 16 + quad * 4 + reg) * LDO + nt * 16 + col] = oacc[mt][nt][reg];
    __syncthreads();
    if (t < 32)
        pls[(tid * 2 + half) * 32 + t] = lred[t] + lred[32 + t] + lred[64 + t] + lred[96 + t];
    float* pob = po + ((long)tid * 2 + half) * 2048;
#pragma unroll
    for (int j = 0; j < 8; ++j) {
        int e = t + 256 * j, r = e >> 6, c = e & 63;
        pob[e] = o_red[r * LDO + c] + o_red[(32 + r) * LDO + c]
               + o_red[(64 + r) * LDO + c] + o_red[(96 + r) * LDO + c];
    }
}

// ---------- combine: out = (O0+O1)/(l0+l1) ----------
__global__ __launch_bounds__(256) void combine(
    const float* __restrict__ po, const float* __restrict__ pls, float* __restrict__ out)
{
    const int g = blockIdx.x;
    const long orow = (((long)(g >> 7)) * Tt + (long)(g & 127) * 32) * Hh;
    const float* p0 = po + (long)g * 2 * 2048;
    const float* p1 = p0 + 2048;
    const float* l0 = pls + g * 2 * 32;
    const float* l1 = l0 + 32;
    const int t = threadIdx.x;
#pragma unroll
    for (int j = 0; j < 8; ++j) {
        int e = t + 256 * j, r = e >> 6;
        out[orow + e] = (p0[e] + p1[e]) / (l0[r] + l1[r]);
    }
}

extern "C" void kernel_launch(void* const* d_in, const int* in_sizes, int n_in,
                              void* d_out, int out_size, void* d_ws, size_t ws_size,
                              hipStream_t stream)
{
    const float* x  = (const float*)d_in[0];
    const float* Wq = (const float*)d_in[1];
    const float* Wk = (const float*)d_in[2];
    const float* Wv = (const float*)d_in[3];
    float* outp = (float*)d_out;

    unsigned short* wt = (unsigned short*)d_ws;       // 192*1024 bf16 (384 KB)
    unsigned short* qb = wt + 196608;                 // 2 MB
    unsigned short* kb = qb + 1048576;                // 2 MB
    unsigned short* vt = kb + 1048576;                // V^T [b][h][t] (2 MB)
    float* po   = (float*)(vt + 1048576);             // [512][2][2048] (8 MB)
    float* pls  = po + 2097152;                       // [512][2][32]

    wt_build<<<dim3(768), dim3(256), 0, stream>>>(Wq, Wk, Wv, wt);
    qkv_gemm<<<dim3(512), dim3(256), 0, stream>>>(x, wt, qb, kb, vt);
    attn<<<dim3(1024), dim3(256), 0, stream>>>(qb, kb, vt, po, pls);
    combine<<<dim3(512), dim3(256), 0, stream>>>(po, pls, outp);
}

// Round 9
// 180.027 us; speedup vs baseline: 1.0246x; 1.0246x over previous
//
#include <hip/hip_runtime.h>
#include <math.h>

#define Tt 4096
#define Cc 1024
#define Hh 64

typedef __attribute__((ext_vector_type(8))) short bf16x8;
typedef __attribute__((ext_vector_type(4))) float f32x4;
typedef unsigned int u32;

__device__ inline unsigned short f2bf(float f) {
    unsigned u = __float_as_uint(f);
    u = (u + 0x7FFFu + ((u >> 16) & 1u)) >> 16;   // RNE
    return (unsigned short)u;
}

__device__ inline u32 pk2bf(float a, float b) {
#if __has_builtin(__builtin_amdgcn_cvt_pk_bf16_f32)
    typedef __attribute__((ext_vector_type(2))) __bf16 bf16x2_t;
    bf16x2_t v = __builtin_amdgcn_cvt_pk_bf16_f32(a, b);
    return __builtin_bit_cast(u32, v);
#else
    return (u32)f2bf(a) | ((u32)f2bf(b) << 16);
#endif
}

__device__ inline bf16x8 pack8(float4 lo, float4 hi) {
    union { u32 u[4]; bf16x8 v; } r;
    r.u[0] = pk2bf(lo.x, lo.y); r.u[1] = pk2bf(lo.z, lo.w);
    r.u[2] = pk2bf(hi.x, hi.y); r.u[3] = pk2bf(hi.z, hi.w);
    return r.v;
}

// ---------- W^T bf16 [192][1024] (kScale folded into Wq) ----------
__global__ __launch_bounds__(256) void wt_build(
    const float* __restrict__ Wq, const float* __restrict__ Wk,
    const float* __restrict__ Wv, unsigned short* __restrict__ Wt)
{
    int e = blockIdx.x * 256 + threadIdx.x;   // 0..196607
    int k = e & 1023, n = e >> 10;
    float v;
    if (n < 64)       v = Wq[k * 64 + n] * 0.03125f;   // fold 1024^-0.5 into Q
    else if (n < 128) v = Wk[k * 64 + (n - 64)];
    else              v = Wv[k * 64 + (n - 128)];
    Wt[n * 1024 + k] = f2bf(v);
}

// ---------- QKV GEMM: register-resident depth-2 pipeline, no LDS, no barriers ----------
// 512 blocks x 4 waves; tile 32M x 192N; BK=64 (16 steps, fully unrolled).
// amdgpu_waves_per_eu(1,2): cap the scheduler's occupancy TARGET at 2 waves/EU so it
// budgets up to 256 VGPR and keeps the prefetch slots in registers. Round 8 lesson:
// __launch_bounds__(256,2) only sets the MIN waves/EU -> scheduler still targeted 8
// waves/EU, self-capped at 44 VGPR, and sank every load to its use (61 us).
__global__ __launch_bounds__(256) __attribute__((amdgpu_waves_per_eu(1, 2)))
void qkv_gemm(
    const float* __restrict__ x, const unsigned short* __restrict__ wt,
    unsigned short* __restrict__ qb, unsigned short* __restrict__ kb,
    unsigned short* __restrict__ vt)
{
    const int t = threadIdx.x, w = t >> 6, lane = t & 63;
    const int col = lane & 15, quad = lane >> 4;
    const int rowbase = (int)blockIdx.x * 32;

    const float* aR0 = x + (long)(rowbase + col) * Cc + quad * 8;        // m-tile 0 row
    const float* aR1 = x + (long)(rowbase + 16 + col) * Cc + quad * 8;   // m-tile 1 row
    const unsigned short* bR0 = wt + (long)((3 * w + 0) * 16 + col) * Cc + quad * 8;
    const unsigned short* bR1 = wt + (long)((3 * w + 1) * 16 + col) * Cc + quad * 8;
    const unsigned short* bR2 = wt + (long)((3 * w + 2) * 16 + col) * Cc + quad * 8;

    float4 ar[2][8];     // [slot][m*4 + kc*2 + half]
    bf16x8 br[2][6];     // [slot][nt*2 + kc]
    f32x4 acc[2][3];
#pragma unroll
    for (int mt = 0; mt < 2; ++mt)
#pragma unroll
        for (int nt = 0; nt < 3; ++nt) acc[mt][nt] = (f32x4){0.f, 0.f, 0.f, 0.f};

    auto issue = [&](int slot, int kk) {
#pragma unroll
        for (int kc = 0; kc < 2; ++kc) {
            int ko = kk + kc * 32;
            ar[slot][0 + kc * 2] = *(const float4*)(aR0 + ko);
            ar[slot][1 + kc * 2] = *(const float4*)(aR0 + ko + 4);
            ar[slot][4 + kc * 2] = *(const float4*)(aR1 + ko);
            ar[slot][5 + kc * 2] = *(const float4*)(aR1 + ko + 4);
            br[slot][0 + kc]     = *(const bf16x8*)(bR0 + ko);
            br[slot][2 + kc]     = *(const bf16x8*)(bR1 + ko);
            br[slot][4 + kc]     = *(const bf16x8*)(bR2 + ko);
        }
    };

    issue(0, 0);
    issue(1, 64);

#pragma unroll
    for (int s = 0; s < 16; ++s) {
        const int sl = s & 1;
        bf16x8 af[2][2];
        af[0][0] = pack8(ar[sl][0], ar[sl][1]);
        af[0][1] = pack8(ar[sl][2], ar[sl][3]);
        af[1][0] = pack8(ar[sl][4], ar[sl][5]);
        af[1][1] = pack8(ar[sl][6], ar[sl][7]);
#pragma unroll
        for (int nt = 0; nt < 3; ++nt)
#pragma unroll
            for (int kc = 0; kc < 2; ++kc) {
                acc[0][nt] = __builtin_amdgcn_mfma_f32_16x16x32_bf16(af[0][kc], br[sl][nt * 2 + kc], acc[0][nt], 0, 0, 0);
                acc[1][nt] = __builtin_amdgcn_mfma_f32_16x16x32_bf16(af[1][kc], br[sl][nt * 2 + kc], acc[1][nt], 0, 0, 0);
            }
        if (s + 2 < 16) issue(sl, (s + 2) * 64);
    }

    // epilogue: C layout col=lane&15, row=quad*4+reg
    const long b = rowbase >> 12;
    const int tloc0 = (rowbase & 4095) + quad * 4;
#pragma unroll
    for (int mt = 0; mt < 2; ++mt)
#pragma unroll
        for (int nt = 0; nt < 3; ++nt) {
            int ng = 3 * w + nt, n = ng * 16 + col;
            int row = rowbase + mt * 16 + quad * 4;
            if (ng < 4) {
#pragma unroll
                for (int reg = 0; reg < 4; ++reg)
                    qb[(long)(row + reg) * Hh + n] = f2bf(acc[mt][nt][reg]);
            } else if (ng < 8) {
#pragma unroll
                for (int reg = 0; reg < 4; ++reg)
                    kb[(long)(row + reg) * Hh + (n - 64)] = f2bf(acc[mt][nt][reg]);
            } else {
                int h = n - 128;
                ushort4 pk = { f2bf(acc[mt][nt][0]), f2bf(acc[mt][nt][1]),
                               f2bf(acc[mt][nt][2]), f2bf(acc[mt][nt][3]) };
                *(ushort4*)&vt[b * Hh * Tt + (long)h * Tt + tloc0 + mt * 16] = pk;
            }
        }
}

// ---------- flash attention (round-4 proven config) ----------
// 1024 blocks = 512 tiles x 2 key-halves, LPT order. Static-max softmax, barrier-free K-loop.
// pl in its OWN LDS region (total 49.7 KB -> scheduler occupancy target 3 blocks/CU ->
// ~170 VGPR budget -> no in-loop spills). DO NOT shrink LDS below ~41 KB (rounds 5/6).
#define LDP 56
#define LDO 68

__global__ __launch_bounds__(256) void attn(
    const unsigned short* __restrict__ qg, const unsigned short* __restrict__ kg,
    const unsigned short* __restrict__ vtg,
    float* __restrict__ po, float* __restrict__ pls)
{
    __shared__ __align__(16) char smem[49664];
    float* o_red       = (float*)smem;                      // 34816 B
    float* lred        = (float*)(smem + 34816);            // 512 B
    unsigned short* pl = (unsigned short*)(smem + 35328);   // 14336 B

    const int p    = blockIdx.x;
    const int qt   = 127 - (p >> 3);
    const int b    = p & 3;
    const int half = (p >> 2) & 1;
    const int tid  = (b << 7) | qt;
    const long qrow0 = (long)b * Tt + qt * 32;
    const int nkt = qt + 1;
    const int n0  = (nkt + 1) >> 1;
    const int cnt = half ? (nkt - n0) : n0;
    const int ust = half ? n0 : 0;

    const int t = threadIdx.x, w = t >> 6, lane = t & 63;
    const int col = lane & 15, quad = lane >> 4;
    const int plbase = w * 32 * LDP;

    bf16x8 qf[2][2];
#pragma unroll
    for (int mt = 0; mt < 2; ++mt)
#pragma unroll
        for (int kc = 0; kc < 2; ++kc)
            qf[mt][kc] = *(const bf16x8*)&qg[(qrow0 + mt * 16 + col) * Hh + kc * 32 + quad * 8];

    f32x4 oacc[2][4];
#pragma unroll
    for (int mt = 0; mt < 2; ++mt)
#pragma unroll
        for (int nt = 0; nt < 4; ++nt) oacc[mt][nt] = (f32x4){0.f, 0.f, 0.f, 0.f};
    float lsum[2][4] = {{0.f,0.f,0.f,0.f},{0.f,0.f,0.f,0.f}};

    for (int iu = w; iu < cnt; iu += 4) {
        const int u = ust + iu;
        const long krow0 = (long)b * Tt + u * 32;
        bf16x8 kf[2][2];
#pragma unroll
        for (int nt = 0; nt < 2; ++nt)
#pragma unroll
            for (int kc = 0; kc < 2; ++kc)
                kf[nt][kc] = *(const bf16x8*)&kg[(krow0 + nt * 16 + col) * Hh + kc * 32 + quad * 8];
        f32x4 s[2][2];
#pragma unroll
        for (int mt = 0; mt < 2; ++mt)
#pragma unroll
            for (int nt = 0; nt < 2; ++nt) {
                s[mt][nt] = (f32x4){0.f, 0.f, 0.f, 0.f};
#pragma unroll
                for (int kc = 0; kc < 2; ++kc)
                    s[mt][nt] = __builtin_amdgcn_mfma_f32_16x16x32_bf16(qf[mt][kc], kf[nt][kc], s[mt][nt], 0, 0, 0);
            }
#pragma unroll
        for (int mt = 0; mt < 2; ++mt)
#pragma unroll
            for (int reg = 0; reg < 4; ++reg) {
                int rloc = mt * 16 + quad * 4 + reg;
                if (u == qt) {                       // diagonal: mask key_local > row_local
                    if (col > rloc)      s[mt][0][reg] = -INFINITY;
                    if (16 + col > rloc) s[mt][1][reg] = -INFINITY;
                }
                float p0 = __expf(s[mt][0][reg]);
                float p1 = __expf(s[mt][1][reg]);
                lsum[mt][reg] += p0 + p1;
                pl[plbase + rloc * LDP + col]      = f2bf(p0);
                pl[plbase + rloc * LDP + 16 + col] = f2bf(p1);
            }
        bf16x8 af0 = *(const bf16x8*)&pl[plbase + col * LDP + quad * 8];
        bf16x8 af1 = *(const bf16x8*)&pl[plbase + (16 + col) * LDP + quad * 8];
#pragma unroll
        for (int nt = 0; nt < 4; ++nt) {
            bf16x8 vf = *(const bf16x8*)&vtg[((long)b * Hh + nt * 16 + col) * Tt + u * 32 + quad * 8];
            oacc[0][nt] = __builtin_amdgcn_mfma_f32_16x16x32_bf16(af0, vf, oacc[0][nt], 0, 0, 0);
            oacc[1][nt] = __builtin_amdgcn_mfma_f32_16x16x32_bf16(af1, vf, oacc[1][nt], 0, 0, 0);
        }
    }

#pragma unroll
    for (int mt = 0; mt < 2; ++mt)
#pragma unroll
        for (int reg = 0; reg < 4; ++reg) {
            float l = lsum[mt][reg];
            l += __shfl_xor(l, 1); l += __shfl_xor(l, 2);
            l += __shfl_xor(l, 4); l += __shfl_xor(l, 8);
            if (col == 0) lred[w * 32 + mt * 16 + quad * 4 + reg] = l;
        }
#pragma unroll
    for (int mt = 0; mt < 2; ++mt)
#pragma unroll
        for (int nt = 0; nt < 4; ++nt)
#pragma unroll
            for (int reg = 0; reg < 4; ++reg)
                o_red[(w * 32 + mt * 16 + quad * 4 + reg) * LDO + nt * 16 + col] = oacc[mt][nt][reg];
    __syncthreads();
    if (t < 32)
        pls[(tid * 2 + half) * 32 + t] = lred[t] + lred[32 + t] + lred[64 + t] + lred[96 + t];
    float* pob = po + ((long)tid * 2 + half) * 2048;
#pragma unroll
    for (int j = 0; j < 8; ++j) {
        int e = t + 256 * j, r = e >> 6, c = e & 63;
        pob[e] = o_red[r * LDO + c] + o_red[(32 + r) * LDO + c]
               + o_red[(64 + r) * LDO + c] + o_red[(96 + r) * LDO + c];
    }
}

// ---------- combine: out = (O0+O1)/(l0+l1) ----------
__global__ __launch_bounds__(256) void combine(
    const float* __restrict__ po, const float* __restrict__ pls, float* __restrict__ out)
{
    const int g = blockIdx.x;
    const long orow = (((long)(g >> 7)) * Tt + (long)(g & 127) * 32) * Hh;
    const float* p0 = po + (long)g * 2 * 2048;
    const float* p1 = p0 + 2048;
    const float* l0 = pls + g * 2 * 32;
    const float* l1 = l0 + 32;
    const int t = threadIdx.x;
#pragma unroll
    for (int j = 0; j < 8; ++j) {
        int e = t + 256 * j, r = e >> 6;
        out[orow + e] = (p0[e] + p1[e]) / (l0[r] + l1[r]);
    }
}

extern "C" void kernel_launch(void* const* d_in, const int* in_sizes, int n_in,
                              void* d_out, int out_size, void* d_ws, size_t ws_size,
                              hipStream_t stream)
{
    const float* x  = (const float*)d_in[0];
    const float* Wq = (const float*)d_in[1];
    const float* Wk = (const float*)d_in[2];
    const float* Wv = (const float*)d_in[3];
    float* outp = (float*)d_out;

    unsigned short* wt = (unsigned short*)d_ws;       // 192*1024 bf16 (384 KB)
    unsigned short* qb = wt + 196608;                 // 2 MB
    unsigned short* kb = qb + 1048576;                // 2 MB
    unsigned short* vt = kb + 1048576;                // V^T [b][h][t] (2 MB)
    float* po   = (float*)(vt + 1048576);             // [512][2][2048] (8 MB)
    float* pls  = po + 2097152;                       // [512][2][32]

    wt_build<<<dim3(768), dim3(256), 0, stream>>>(Wq, Wk, Wv, wt);
    qkv_gemm<<<dim3(512), dim3(256), 0, stream>>>(x, wt, qb, kb, vt);
    attn<<<dim3(1024), dim3(256), 0, stream>>>(qb, kb, vt, po, pls);
    combine<<<dim3(512), dim3(256), 0, stream>>>(po, pls, outp);
}